// Round 9
// baseline (333.284 us; speedup 1.0000x reference)
//
#include <hip/hip_runtime.h>
#include <hip/hip_bf16.h>
#include <stdint.h>

typedef unsigned short u16;
typedef short bf16x8 __attribute__((ext_vector_type(8)));
typedef u16   u16x8  __attribute__((ext_vector_type(8)));
typedef u16   u16x4  __attribute__((ext_vector_type(4)));
typedef float f32x4  __attribute__((ext_vector_type(4)));

__device__ inline u16 f2bf(float f) {
    uint32_t u = __builtin_bit_cast(uint32_t, f);
    uint32_t r = (u + 0x7FFFu + ((u >> 16) & 1u)) >> 16;
    return (u16)r;
}

__device__ inline void gload16(const void* g, void* l) {
    __builtin_amdgcn_global_load_lds((const __attribute__((address_space(1))) void*)g,
                                     (__attribute__((address_space(3))) void*)l, 16, 0, 0);
}

__device__ inline void pin_barrier() {
    __builtin_amdgcn_sched_barrier(0);
    __builtin_amdgcn_s_barrier();
    __builtin_amdgcn_sched_barrier(0);
}

#define MFMA16(a, b, c) __builtin_amdgcn_mfma_f32_16x16x32_bf16((a), (b), (c), 0, 0, 0)

// ---------------- prep: gather even rows of x, cast to bf16 -----------------
__global__ __launch_bounds__(256) void k_prep_xe(const float* __restrict__ x,
                                                 u16* __restrict__ xe) {
    int row = blockIdx.x;              // 0..8191
    int b = row >> 12, tt = row & 4095;
    const float* src = x + ((size_t)b * 8192 + 2 * (size_t)tt) * 1024;
    float4 v = ((const float4*)src)[threadIdx.x];
    u16x4 o = { f2bf(v.x), f2bf(v.y), f2bf(v.z), f2bf(v.w) };
    *(u16x4*)(xe + (size_t)row * 1024 + threadIdx.x * 4) = o;
}

// ---------------- prep: transpose + cast weights to B^T layout --------------
__global__ __launch_bounds__(256) void k_transpose_cast(
    const float* __restrict__ src, u16* __restrict__ dst,
    int srcCols, size_t srcLayerStride, int dstStride, int dstRowPer, int dstColPer) {
    int k0 = blockIdx.x * 64, e0 = blockIdx.y * 64, layer = blockIdx.z;
    const float* s = src + (size_t)layer * srcLayerStride;
    __shared__ u16 T[64][66];
    int t = threadIdx.x;
#pragma unroll
    for (int p = 0; p < 16; ++p) {
        int l = p * 256 + t;
        int kl = l >> 6, el = l & 63;
        T[kl][el] = f2bf(s[(size_t)(k0 + kl) * srcCols + e0 + el]);
    }
    __syncthreads();
    int rowBase = layer * dstRowPer + e0;
    int colBase = layer * dstColPer + k0;
#pragma unroll
    for (int p = 0; p < 16; ++p) {
        int l = p * 256 + t;
        int eo = l >> 6, ko = l & 63;
        dst[(size_t)(rowBase + eo) * dstStride + colBase + ko] = T[ko][eo];
    }
}

// ========== 256x256 region-phase GEMM (m201-style): C = A @ BT^T + bias =====
// BK=64, 2 LDS tile-buffers (64KB each). Per tile: 4 phases; phase p = one
// 128x128 C-quadrant (R0:M0N0, R1:M1N0, R2:M1N1, R3:M0N1) over full K=64 ->
// every phase touches exactly ONE A-half + ONE B-half of LDS; A/B frags are
// reused across adjacent quadrants (reads/phase: 12,4,8,4). Phase p stages one
// 16KB half-tile unit of tile t+1 (order UA0,UB0,UA1,UB1); vmcnt(4) at each
// phase (2 units in flight, never 0) confirms exactly the unit the NEXT
// phase reads; barrier makes it cross-wave. 16 MFMA/wave/phase.
// Swizzle: 128B rows, 16B-slot low2 ^= (row>>1)&3 (R8-proven), inverse on the
// global staging source (linear gload_lds dest), swizzled ds_read.
// Requires: K%64==0, M%256==0, N%256==0, grid%8==0.
__global__ __launch_bounds__(512, 2) void k_gemm8(
    const u16* __restrict__ A, const u16* __restrict__ B, u16* __restrict__ C,
    const float* __restrict__ bias, int K, int lda, int ldb, int ldc,
    int gxmask, int gxshift) {
    __shared__ __align__(16) char smem[131072];
    const int tid = threadIdx.x, lane = tid & 63, wave = tid >> 6;
    const int wr = wave >> 1, wc = wave & 1;   // 4M x 2N inside a quadrant

    // bijective XCD swizzle (grid multiple of 8)
    const int nwg = gridDim.x, bid = blockIdx.x;
    const int cpx = nwg >> 3;
    const int swz = (bid & 7) * cpx + (bid >> 3);
    const int bx = swz & gxmask, by = swz >> gxshift;
    const int row0 = bx << 8, col0 = by << 8;

    const size_t lda2 = (size_t)lda * 2, ldb2 = (size_t)ldb * 2;

    // staging sources (inverse-swizzled): chunk c = tid + i*512 covers local
    // row c>>3, LDS slot c&7; source 16B-chunk = (c&4) + ((c&3)^((c>>4)&3)).
    const char* pA[2]; const char* pB[2];
#pragma unroll
    for (int i = 0; i < 2; ++i) {
        int c = tid + i * 512;
        int rl = c >> 3;
        int chunk = (c & 4) + ((c & 3) ^ ((c >> 4) & 3));
        pA[i] = (const char*)A + (size_t)(row0 + rl) * lda2 + chunk * 16;
        pB[i] = (const char*)B + (size_t)(col0 + rl) * ldb2 + chunk * 16;
    }
    const int dstOff = tid * 16;

    // per-lane swizzled ds_read offsets (row=base+la, slot=kh*4+(lg^((la>>1)&3)))
    const int la = lane & 15, lg = lane >> 4;
    int loff[2];
#pragma unroll
    for (int kh = 0; kh < 2; ++kh)
        loff[kh] = la * 128 + ((kh * 4 + (lg ^ ((la >> 1) & 3))) << 4);

    f32x4 acc[4][2][4] = {};
    bf16x8 afr[2][2], bfr[4][2];
    const int nt = K >> 6;

    // unit stagers: A rows 0-127 -> buf+0, A rows 128-255 -> buf+16384,
    //               B rows 0-127 -> buf+32768, B rows 128-255 -> buf+49152
#define ST_UA0(sb, kof) do { gload16(pA[0] + (kof), (sb) + dstOff); \
                             gload16(pA[1] + (kof), (sb) + 8192 + dstOff); } while (0)
#define ST_UB0(sb, kof) do { gload16(pB[0] + (kof), (sb) + 32768 + dstOff); \
                             gload16(pB[1] + (kof), (sb) + 40960 + dstOff); } while (0)
#define ST_UA1(sb, kof) do { gload16(pA[0] + (size_t)128 * lda2 + (kof), (sb) + 16384 + dstOff); \
                             gload16(pA[1] + (size_t)128 * lda2 + (kof), (sb) + 24576 + dstOff); } while (0)
#define ST_UB1(sb, kof) do { gload16(pB[0] + (size_t)128 * ldb2 + (kof), (sb) + 49152 + dstOff); \
                             gload16(pB[1] + (size_t)128 * ldb2 + (kof), (sb) + 57344 + dstOff); } while (0)

    // phase: reads (safe via PREVIOUS phase's vmcnt+barrier) | stage | vmcnt(4)
    //        | barrier | lgkmcnt(0) | 16 MFMA | barrier
#define PHASE(p, RM, RN, rb, STG) do { \
        if ((p) != 2) { \
            _Pragma("unroll") for (int m = 0; m < 2; ++m) \
            _Pragma("unroll") for (int kh = 0; kh < 2; ++kh) \
                afr[m][kh] = *(const bf16x8*)((rb) + ((RM) + wr * 32 + m * 16) * 128 + loff[kh]); \
        } \
        if ((p) == 0 || (p) == 2) { \
            _Pragma("unroll") for (int n = 0; n < 4; ++n) \
            _Pragma("unroll") for (int kh = 0; kh < 2; ++kh) \
                bfr[n][kh] = *(const bf16x8*)((rb) + 32768 + ((RN) + wc * 64 + n * 16) * 128 + loff[kh]); \
        } \
        STG; \
        __builtin_amdgcn_sched_barrier(0); \
        asm volatile("s_waitcnt vmcnt(4)" ::: "memory"); \
        pin_barrier(); \
        asm volatile("s_waitcnt lgkmcnt(0)" ::: "memory"); \
        __builtin_amdgcn_sched_barrier(0); \
        __builtin_amdgcn_s_setprio(1); \
        _Pragma("unroll") for (int m = 0; m < 2; ++m) \
        _Pragma("unroll") for (int n = 0; n < 4; ++n) \
        _Pragma("unroll") for (int kh = 0; kh < 2; ++kh) \
            acc[p][m][n] = MFMA16(afr[m][kh], bfr[n][kh], acc[p][m][n]); \
        __builtin_amdgcn_s_setprio(0); \
        pin_barrier(); \
    } while (0)

    // prologue: stage tile 0 (4 units); confirm UA0,UB0; barrier
    ST_UA0(smem, 0); ST_UB0(smem, 0); ST_UA1(smem, 0); ST_UB1(smem, 0);
    __builtin_amdgcn_sched_barrier(0);
    asm volatile("s_waitcnt vmcnt(4)" ::: "memory");
    pin_barrier();

    for (int t = 0; t < nt; ++t) {
        char* rb = smem + (t & 1) * 65536;
        char* sb = smem + ((t & 1) ^ 1) * 65536;
        const size_t kof = (size_t)((t + 1 < nt) ? t + 1 : nt - 1) * 128;
        PHASE(0,   0,   0, rb, ST_UA0(sb, kof));
        PHASE(1, 128,   0, rb, ST_UB0(sb, kof));
        PHASE(2, 128, 128, rb, ST_UA1(sb, kof));
        PHASE(3,   0, 128, rb, ST_UB1(sb, kof));
    }
#undef PHASE
#undef ST_UA0
#undef ST_UB0
#undef ST_UA1
#undef ST_UB1

    // ---- epilogue: LDS-restage -> full-line coalesced bf16 stores ----
    {
        char* cst = smem;
        // drain dead-tail prefetches before overwriting LDS
        __builtin_amdgcn_sched_barrier(0);
        asm volatile("s_waitcnt vmcnt(0)" ::: "memory");
        pin_barrier();
        const int g4 = lg << 2;
        const int RMv[4] = {0, 128, 128, 0}, RNv[4] = {0, 0, 128, 128};
#pragma unroll
        for (int p = 0; p < 4; ++p) {
#pragma unroll
            for (int n = 0; n < 4; ++n) {
                int col = RNv[p] + wc * 64 + n * 16 + la;
                float bs = bias[col0 + col];
#pragma unroll
                for (int m = 0; m < 2; ++m) {
#pragma unroll
                    for (int r = 0; r < 4; ++r) {
                        int row = RMv[p] + wr * 32 + m * 16 + g4 + r;
                        int scol = col ^ (((row >> 2) & 3) << 3);
                        *(u16*)(cst + row * 512 + scol * 2) = f2bf(acc[p][m][n][r] + bs);
                    }
                }
            }
        }
        pin_barrier();
#pragma unroll
        for (int it = 0; it < 16; ++it) {
            int id = it * 512 + tid;       // 16B chunk: row*32 + c16
            int r2 = id >> 5, c16 = id & 31;
            int sc16 = c16 ^ ((r2 >> 2) & 3);
            u16x8 v = *(const u16x8*)(cst + r2 * 512 + sc16 * 16);
            *(u16x8*)((char*)C + ((size_t)(row0 + r2) * ldc + col0) * 2 + c16 * 16) = v;
        }
    }
}

// ====== 256x128 BK=32 GEMM (R8 structure, proven) for the output proj =======
template <int BN, bool BF16OUT>
__global__ __launch_bounds__(512, 2) void k_gemm5(
    const u16* __restrict__ A, const u16* __restrict__ B, void* __restrict__ C,
    const float* __restrict__ bias0, const float* __restrict__ bias1,
    const float* __restrict__ bias2, int K, int lda, int ldb, int ldc,
    int gxmask, int gxshift) {
    constexpr int WN = BN / 64;
    constexpr int WM = 8 / WN;
    constexpr int MFRAG = 256 / (WM * 16);
    constexpr int NBB = BN / 128;
    constexpr int NL = 2 + NBB;
    constexpr int BUFSZ = 16384 + BN * 64;

    __shared__ __align__(16) char smem[131072];
    const int tid = threadIdx.x, lane = tid & 63, wave = tid >> 6;
    const int wr = wave / WN, wc = wave % WN;

    const int nwg = gridDim.x, bid = blockIdx.x;
    const int cpx = nwg >> 3;
    const int swz = (bid & 7) * cpx + (bid >> 3);
    const int bx = swz & gxmask, by = swz >> gxshift;
    const int row0 = bx << 8, col0 = by * BN;

    const size_t lda2 = (size_t)lda * 2, ldb2 = (size_t)ldb * 2;
    const int cSw = ((tid & 3) ^ ((tid >> 3) & 3)) * 16;
    const char* pA0 = (const char*)A + (size_t)(row0 + (tid >> 2)) * lda2 + cSw;
    const char* pB0 = (const char*)B + (size_t)(col0 + (tid >> 2)) * ldb2 + cSw;

#define STA(i, sb, kof) gload16(pA0 + (size_t)(i) * 128 * lda2 + (kof), \
                                (sb) + (i) * 8192 + wave * 1024)
#define STB(i, sb, kof) gload16(pB0 + (size_t)(i) * 128 * ldb2 + (kof), \
                                (sb) + 16384 + (i) * 8192 + wave * 1024)
#define STAGE_ALL(sb, kof) do { \
        STA(0, sb, kof); STA(1, sb, kof); \
        STB(0, sb, kof); if constexpr (NBB == 2) STB(1, sb, kof); } while (0)

    auto WAIT_VM = [] {
        if constexpr (NL == 4) asm volatile("s_waitcnt vmcnt(8)" ::: "memory");
        else                   asm volatile("s_waitcnt vmcnt(6)" ::: "memory");
    };

    const int lane_off = (lane & 15) * 64 +
                         (((lane >> 4) ^ (((lane & 15) >> 1) & 3)) << 4);

    f32x4 acc[MFRAG][4] = {};
    const int nt = K >> 5;

#define TILE_BODY(q, q3, t) do { \
        char* rq = smem + (q) * BUFSZ; \
        char* sq = smem + (q3) * BUFSZ; \
        const char* aRd = rq + wr * (MFRAG * 1024) + lane_off; \
        const char* bRd = rq + 16384 + wc * 4096 + lane_off; \
        bf16x8 af[4], bg[4]; \
        _Pragma("unroll") for (int n = 0; n < 4; ++n) \
            bg[n] = *(const bf16x8*)(bRd + n * 1024); \
        _Pragma("unroll") for (int m = 0; m < 4; ++m) \
            af[m] = *(const bf16x8*)(aRd + m * 1024); \
        { \
            const int ts = ((t) + 3 < nt) ? (t) + 3 : nt - 1; \
            const size_t kof = (size_t)ts * 64; \
            STAGE_ALL(sq, kof); \
        } \
        bf16x8 ag[4]; \
        if constexpr (MFRAG == 8) { \
            _Pragma("unroll") for (int m = 0; m < 4; ++m) \
                ag[m] = *(const bf16x8*)(aRd + (4 + m) * 1024); \
        } \
        __builtin_amdgcn_sched_barrier(0); \
        __builtin_amdgcn_s_setprio(1); \
        _Pragma("unroll") for (int m = 0; m < 4; ++m) \
            _Pragma("unroll") for (int n = 0; n < 4; ++n) \
                acc[m][n] = MFMA16(af[m], bg[n], acc[m][n]); \
        __builtin_amdgcn_s_setprio(0); \
        if constexpr (MFRAG == 8) { \
            __builtin_amdgcn_sched_barrier(0); \
            __builtin_amdgcn_s_setprio(1); \
            _Pragma("unroll") for (int m = 0; m < 4; ++m) \
                _Pragma("unroll") for (int n = 0; n < 4; ++n) \
                    acc[4 + m][n] = MFMA16(ag[m], bg[n], acc[4 + m][n]); \
            __builtin_amdgcn_s_setprio(0); \
        } \
        __builtin_amdgcn_sched_barrier(0); \
        WAIT_VM(); \
        pin_barrier(); \
    } while (0)

    STAGE_ALL(smem + 0 * BUFSZ, 0);
    STAGE_ALL(smem + 1 * BUFSZ, 64);
    STAGE_ALL(smem + 2 * BUFSZ, 128);
    __builtin_amdgcn_sched_barrier(0);
    WAIT_VM();
    pin_barrier();

    for (int t = 0; t < nt; t += 4) {
        TILE_BODY(0, 3, t + 0);
        TILE_BODY(1, 0, t + 1);
        TILE_BODY(2, 1, t + 2);
        TILE_BODY(3, 2, t + 3);
    }
#undef TILE_BODY
#undef STAGE_ALL
#undef STA
#undef STB

    {
        char* cst = smem;
        const int g4 = (lane >> 4) << 2, cl = lane & 15;
        __builtin_amdgcn_sched_barrier(0);
        asm volatile("s_waitcnt vmcnt(0)" ::: "memory");
        pin_barrier();
#pragma unroll
        for (int n = 0; n < 4; ++n) {
            int col = wc * 64 + n * 16 + cl;
            float bs = bias0[col0 + col];
            if (bias1) bs += bias1[col0 + col];
            if (bias2) bs += bias2[col0 + col];
#pragma unroll
            for (int m = 0; m < MFRAG; ++m) {
#pragma unroll
                for (int r = 0; r < 4; ++r) {
                    int row = wr * (MFRAG * 16) + m * 16 + g4 + r;
                    float v = acc[m][n][r] + bs;
                    if (BF16OUT) {
                        int scol = col ^ (((row >> 2) & 3) << 3);
                        *(u16*)(cst + row * 512 + scol * 2) = f2bf(v);
                    } else {
                        int scol = col ^ (((row >> 2) & 3) << 2);
                        *(float*)(cst + row * 512 + scol * 4) = v;
                    }
                }
            }
        }
        pin_barrier();
        const int esz = BF16OUT ? 2 : 4;
#pragma unroll
        for (int it = 0; it < 16; ++it) {
            int id = it * 512 + tid;
            int row = id >> 5, c16 = id & 31;
            int sc16 = c16 ^ ((row >> 2) & 3);
            u16x8 v = *(const u16x8*)(cst + row * 512 + sc16 * 16);
            char* dst = (char*)C + ((size_t)(row0 + row) * ldc + col0) * esz + c16 * 16;
            *(u16x8*)dst = v;
        }
    }
}

// ---------------- attention: one block per (b, segment, head) ---------------
template <int S>
__global__ __launch_bounds__(256) void k_attn(const u16* __restrict__ qkv,
                                              u16* __restrict__ ab, int layer) {
    constexpr int NCT = S / 16;
    constexpr int RPW = (S == 32) ? 1 : S / 64;
    constexpr int ACTIVE = (S == 32) ? 2 : 4;
    constexpr int KST = S / 32;
    constexpr int VSTRIDE = 2 * S;
    constexpr int VMASK = VSTRIDE / 16 - 1;

    __shared__ __align__(16) char KS[S * 128];
    __shared__ __align__(16) char VTS[64 * VSTRIDE];
    __shared__ __align__(16) char PS[S * VSTRIDE];

    const int per_b = (4096 / S) * 16;
    const int b = blockIdx.x / per_b;
    const int r0 = blockIdx.x % per_b;
    const int n = r0 >> 4, h = r0 & 15;
    const int token0 = b * 4096 + n * S;
    const int colQ = layer * 3072 + h * 64;
    const int tid = threadIdx.x, lane = tid & 63, wave = tid >> 6;

    constexpr int CHUNKS = S / 32;
#pragma unroll
    for (int c = 0; c < CHUNKS; ++c) {
        int lc = c * 256 + tid;
        int row = lc >> 3, off = (lc & 7) * 16;
        const char* base = (const char*)qkv + ((size_t)(token0 + row) * 9216 + colQ) * 2 + off;
        u16x8 kv = *(const u16x8*)(base + 1024 * 2);
        *(u16x8*)(KS + row * 128 + (off ^ ((row & 7) << 4))) = kv;
        u16x8 vv = *(const u16x8*)(base + 2048 * 2);
        int cb = off >> 1;
#pragma unroll
        for (int e = 0; e < 8; ++e) {
            int col = cb + e;
            *(u16*)(VTS + col * VSTRIDE + ((row * 2) ^ ((col & VMASK) << 4))) = vv[e];
        }
    }
    __syncthreads();

    f32x4 sacc[RPW][NCT] = {};
    if (wave < ACTIVE) {
#pragma unroll
        for (int rl = 0; rl < RPW; ++rl) {
            int rt = wave * RPW + rl;
#pragma unroll
            for (int ks2 = 0; ks2 < 2; ++ks2) {
                int qrow = token0 + rt * 16 + (lane & 15);
                int kbyte = ks2 * 64 + ((lane >> 4) << 4);
                bf16x8 aq = *(const bf16x8*)((const char*)qkv +
                              ((size_t)qrow * 9216 + colQ) * 2 + kbyte);
#pragma unroll
                for (int ct = 0; ct < NCT; ++ct) {
                    int krow = ct * 16 + (lane & 15);
                    bf16x8 bk = *(const bf16x8*)(KS + krow * 128 + (kbyte ^ ((krow & 7) << 4)));
                    sacc[rl][ct] = MFMA16(aq, bk, sacc[rl][ct]);
                }
            }
        }
#pragma unroll
        for (int rl = 0; rl < RPW; ++rl) {
            int rt = wave * RPW + rl;
#pragma unroll
            for (int r = 0; r < 4; ++r) {
                float vals[NCT];
                float m = -1e30f;
#pragma unroll
                for (int ct = 0; ct < NCT; ++ct) {
                    vals[ct] = sacc[rl][ct][r] * 0.125f;
                    m = fmaxf(m, vals[ct]);
                }
#pragma unroll
                for (int d = 1; d < 16; d <<= 1) m = fmaxf(m, __shfl_xor(m, d, 64));
                float sum = 0.f;
#pragma unroll
                for (int ct = 0; ct < NCT; ++ct) {
                    float p = exp2f((vals[ct] - m) * 1.44269504f);
                    vals[ct] = p;
                    sum += p;
                }
#pragma unroll
                for (int d = 1; d < 16; d <<= 1) sum += __shfl_xor(sum, d, 64);
                float inv = 1.0f / sum;
                int row = rt * 16 + ((lane >> 4) << 2) + r;
#pragma unroll
                for (int ct = 0; ct < NCT; ++ct) {
                    int col = ct * 16 + (lane & 15);
                    *(u16*)(PS + row * VSTRIDE + ((col * 2) ^ ((row & VMASK) << 4))) =
                        f2bf(vals[ct] * inv);
                }
            }
        }
    }
    __syncthreads();

    if (wave < ACTIVE) {
        const int colA = layer * 1024 + h * 64;
#pragma unroll
        for (int rl = 0; rl < RPW; ++rl) {
            int rt = wave * RPW + rl;
            f32x4 oacc[4] = {};
#pragma unroll
            for (int ks2 = 0; ks2 < KST; ++ks2) {
                int kbyte = ks2 * 64 + ((lane >> 4) << 4);
                int prow = rt * 16 + (lane & 15);
                bf16x8 ap = *(const bf16x8*)(PS + prow * VSTRIDE + (kbyte ^ ((prow & VMASK) << 4)));
#pragma unroll
                for (int ct = 0; ct < 4; ++ct) {
                    int vcol = ct * 16 + (lane & 15);
                    bf16x8 bv = *(const bf16x8*)(VTS + vcol * VSTRIDE + (kbyte ^ ((vcol & VMASK) << 4)));
                    oacc[ct] = MFMA16(ap, bv, oacc[ct]);
                }
            }
#pragma unroll
            for (int ct = 0; ct < 4; ++ct) {
#pragma unroll
                for (int r = 0; r < 4; ++r) {
                    int row = token0 + rt * 16 + ((lane >> 4) << 2) + r;
                    int col = colA + ct * 16 + (lane & 15);
                    ab[(size_t)row * 3072 + col] = f2bf(oacc[ct][r]);
                }
            }
        }
    }
}

// ---------------------------------------------------------------------------
extern "C" void kernel_launch(void* const* d_in, const int* in_sizes, int n_in,
                              void* d_out, int out_size, void* d_ws, size_t ws_size,
                              hipStream_t stream) {
    const float* x    = (const float*)d_in[0];
    const float* Wqkv = (const float*)d_in[1];
    const float* bqkv = (const float*)d_in[2];
    const float* Wo   = (const float*)d_in[3];
    const float* bo   = (const float*)d_in[4];

    char* ws = (char*)d_ws;
    u16* XE    = (u16*)(ws);                       // [8192][1024]
    u16* WQKVT = (u16*)(ws + 16777216);            // [9216][1024]
    u16* WOT   = (u16*)(ws + 35651584);            // [1024][3072]
    u16* QKVB  = (u16*)(ws + 41943040);            // [8192][9216]
    u16* ABUF  = (u16*)(ws + 192937984);           // [8192][3072]

    k_prep_xe<<<8192, 256, 0, stream>>>(x, XE);
    k_transpose_cast<<<dim3(16, 48, 3), 256, 0, stream>>>(
        Wqkv, WQKVT, 3072, (size_t)1024 * 3072, 1024, 3072, 0);
    k_transpose_cast<<<dim3(16, 16, 3), 256, 0, stream>>>(
        Wo, WOT, 1024, (size_t)1024 * 1024, 3072, 0, 1024);

    // QKV projection for all 3 layers: [8192,1024] @ [1024,9216]
    // grid = 32 x 36 = 1152 blocks (bx fastest: mask 31, shift 5)
    k_gemm8<<<dim3(1152), 512, 0, stream>>>(
        XE, WQKVT, QKVB, bqkv, 1024, 1024, 1024, 9216, 31, 5);

    // dilated segment attention per layer
    k_attn<32><<<4096, 256, 0, stream>>>(QKVB, ABUF, 0);
    k_attn<64><<<2048, 256, 0, stream>>>(QKVB, ABUF, 1);
    k_attn<128><<<1024, 256, 0, stream>>>(QKVB, ABUF, 2);

    // fused output projection + layer sum: [8192,3072] @ [3072,1024]
    // grid = 32 x 8 = 256 blocks
    k_gemm5<128, false><<<dim3(256), 512, 0, stream>>>(
        ABUF, WOT, d_out, bo, bo + 1024, bo + 2048, 3072, 3072, 3072, 1024, 31, 5);
}

// Round 10
// 328.281 us; speedup vs baseline: 1.0152x; 1.0152x over previous
//
#include <hip/hip_runtime.h>
#include <hip/hip_bf16.h>
#include <stdint.h>

typedef unsigned short u16;
typedef short bf16x8 __attribute__((ext_vector_type(8)));
typedef u16   u16x8  __attribute__((ext_vector_type(8)));
typedef u16   u16x4  __attribute__((ext_vector_type(4)));
typedef float f32x4  __attribute__((ext_vector_type(4)));

__device__ inline u16 f2bf(float f) {
    uint32_t u = __builtin_bit_cast(uint32_t, f);
    uint32_t r = (u + 0x7FFFu + ((u >> 16) & 1u)) >> 16;
    return (u16)r;
}

__device__ inline void gload16(const void* g, void* l) {
    __builtin_amdgcn_global_load_lds((const __attribute__((address_space(1))) void*)g,
                                     (__attribute__((address_space(3))) void*)l, 16, 0, 0);
}

__device__ inline void pin_barrier() {
    __builtin_amdgcn_sched_barrier(0);
    __builtin_amdgcn_s_barrier();
    __builtin_amdgcn_sched_barrier(0);
}

#define MFMA16(a, b, c) __builtin_amdgcn_mfma_f32_16x16x32_bf16((a), (b), (c), 0, 0, 0)

// ---------------- prep: gather even rows of x, cast to bf16 -----------------
__global__ __launch_bounds__(256) void k_prep_xe(const float* __restrict__ x,
                                                 u16* __restrict__ xe) {
    int row = blockIdx.x;              // 0..8191
    int b = row >> 12, tt = row & 4095;
    const float* src = x + ((size_t)b * 8192 + 2 * (size_t)tt) * 1024;
    float4 v = ((const float4*)src)[threadIdx.x];
    u16x4 o = { f2bf(v.x), f2bf(v.y), f2bf(v.z), f2bf(v.w) };
    *(u16x4*)(xe + (size_t)row * 1024 + threadIdx.x * 4) = o;
}

// ---------------- prep: transpose + cast weights to B^T layout --------------
__global__ __launch_bounds__(256) void k_transpose_cast(
    const float* __restrict__ src, u16* __restrict__ dst,
    int srcCols, size_t srcLayerStride, int dstStride, int dstRowPer, int dstColPer) {
    int k0 = blockIdx.x * 64, e0 = blockIdx.y * 64, layer = blockIdx.z;
    const float* s = src + (size_t)layer * srcLayerStride;
    __shared__ u16 T[64][66];
    int t = threadIdx.x;
#pragma unroll
    for (int p = 0; p < 16; ++p) {
        int l = p * 256 + t;
        int kl = l >> 6, el = l & 63;
        T[kl][el] = f2bf(s[(size_t)(k0 + kl) * srcCols + e0 + el]);
    }
    __syncthreads();
    int rowBase = layer * dstRowPer + e0;
    int colBase = layer * dstColPer + k0;
#pragma unroll
    for (int p = 0; p < 16; ++p) {
        int l = p * 256 + t;
        int eo = l >> 6, ko = l & 63;
        dst[(size_t)(rowBase + eo) * dstStride + colBase + ko] = T[ko][eo];
    }
}

// ========== 256x256 region-phase GEMM (m201-style): C = A @ BT^T + bias =====
// BK=64, 2 LDS tile-buffers (64KB each). Per tile: 4 phases; phase p = one
// 128x128 C-quadrant (R0:M0N0, R1:M1N0, R2:M1N1, R3:M0N1) over full K=64.
// Phase p stages one 16KB half-tile unit of tile t+1 (order UA0,UB0,UA1,UB1);
// vmcnt(4) per phase (2 units in flight, never 0) confirms exactly the unit
// the NEXT phase reads (ledger verified phase-by-phase). 16 MFMA/wave/phase.
// Swizzle (R10 FIX): 128B rows, byte = row*128 + (chunk ^ (row&7))*16 — full
// 3-bit XOR => 8 slots x 4 banks = 32 banks, exactly 2 lanes/bank (free).
// Inverse-swizzled global source (linear gload_lds dest), swizzled ds_read.
// Requires: K%64==0, M%256==0, N%256==0, grid%8==0.
__global__ __launch_bounds__(512, 2) void k_gemm8(
    const u16* __restrict__ A, const u16* __restrict__ B, u16* __restrict__ C,
    const float* __restrict__ bias, int K, int lda, int ldb, int ldc,
    int gxmask, int gxshift) {
    __shared__ __align__(16) char smem[131072];
    const int tid = threadIdx.x, lane = tid & 63, wave = tid >> 6;
    const int wr = wave >> 1, wc = wave & 1;   // 4M x 2N inside a quadrant

    // bijective XCD swizzle (grid multiple of 8)
    const int nwg = gridDim.x, bid = blockIdx.x;
    const int cpx = nwg >> 3;
    const int swz = (bid & 7) * cpx + (bid >> 3);
    const int bx = swz & gxmask, by = swz >> gxshift;
    const int row0 = bx << 8, col0 = by << 8;

    const size_t lda2 = (size_t)lda * 2, ldb2 = (size_t)ldb * 2;

    // staging sources (inverse-swizzled, full 3-bit XOR): thread covers local
    // row tid>>3, LDS slot tid&7; source 16B-chunk = (tid&7) ^ ((tid>>3)&7).
    const int sRow = tid >> 3;
    const int sChunk = (tid & 7) ^ (sRow & 7);
    const char* pA0 = (const char*)A + (size_t)(row0 + sRow) * lda2 + sChunk * 16;
    const char* pB0 = (const char*)B + (size_t)(col0 + sRow) * ldb2 + sChunk * 16;
    const int dstOff = tid * 16;

    // per-lane swizzled ds_read offsets: row=base+la, byte=row*128+((kh*4+lg)^(la&7))*16
    const int la = lane & 15, lg = lane >> 4;
    int loff[2];
#pragma unroll
    for (int kh = 0; kh < 2; ++kh)
        loff[kh] = la * 128 + (((kh * 4 + lg) ^ (la & 7)) << 4);

    f32x4 acc[4][2][4] = {};
    bf16x8 afr[2][2], bfr[4][2];
    const int nt = K >> 6;

    // unit stagers (each = 2 gloads/thread, 16KB):
    // A rows 0-127 -> buf+0, A rows 128-255 -> buf+16384,
    // B rows 0-127 -> buf+32768, B rows 128-255 -> buf+49152
#define ST_UA0(sb, kof) do { gload16(pA0 + (kof), (sb) + dstOff); \
                             gload16(pA0 + (size_t)64 * lda2 + (kof), (sb) + 8192 + dstOff); } while (0)
#define ST_UB0(sb, kof) do { gload16(pB0 + (kof), (sb) + 32768 + dstOff); \
                             gload16(pB0 + (size_t)64 * ldb2 + (kof), (sb) + 40960 + dstOff); } while (0)
#define ST_UA1(sb, kof) do { gload16(pA0 + (size_t)128 * lda2 + (kof), (sb) + 16384 + dstOff); \
                             gload16(pA0 + (size_t)192 * lda2 + (kof), (sb) + 24576 + dstOff); } while (0)
#define ST_UB1(sb, kof) do { gload16(pB0 + (size_t)128 * ldb2 + (kof), (sb) + 49152 + dstOff); \
                             gload16(pB0 + (size_t)192 * ldb2 + (kof), (sb) + 57344 + dstOff); } while (0)

    // phase: reads (unit confirmed by PREVIOUS phase's vmcnt+barrier) | stage
    //        | vmcnt(4) | barrier | lgkmcnt(0) | 16 MFMA | barrier
#define PHASE(p, RM, RN, rb, STG) do { \
        if ((p) != 2) { \
            _Pragma("unroll") for (int m = 0; m < 2; ++m) \
            _Pragma("unroll") for (int kh = 0; kh < 2; ++kh) \
                afr[m][kh] = *(const bf16x8*)((rb) + ((RM) + wr * 32 + m * 16) * 128 + loff[kh]); \
        } \
        if ((p) == 0 || (p) == 2) { \
            _Pragma("unroll") for (int n = 0; n < 4; ++n) \
            _Pragma("unroll") for (int kh = 0; kh < 2; ++kh) \
                bfr[n][kh] = *(const bf16x8*)((rb) + 32768 + ((RN) + wc * 64 + n * 16) * 128 + loff[kh]); \
        } \
        STG; \
        __builtin_amdgcn_sched_barrier(0); \
        asm volatile("s_waitcnt vmcnt(4)" ::: "memory"); \
        pin_barrier(); \
        asm volatile("s_waitcnt lgkmcnt(0)" ::: "memory"); \
        __builtin_amdgcn_sched_barrier(0); \
        __builtin_amdgcn_s_setprio(1); \
        _Pragma("unroll") for (int m = 0; m < 2; ++m) \
        _Pragma("unroll") for (int n = 0; n < 4; ++n) \
        _Pragma("unroll") for (int kh = 0; kh < 2; ++kh) \
            acc[p][m][n] = MFMA16(afr[m][kh], bfr[n][kh], acc[p][m][n]); \
        __builtin_amdgcn_s_setprio(0); \
        pin_barrier(); \
    } while (0)

    // prologue: stage tile 0 (4 units); confirm UA0,UB0; barrier
    ST_UA0(smem, 0); ST_UB0(smem, 0); ST_UA1(smem, 0); ST_UB1(smem, 0);
    __builtin_amdgcn_sched_barrier(0);
    asm volatile("s_waitcnt vmcnt(4)" ::: "memory");
    pin_barrier();

    for (int t = 0; t < nt; ++t) {
        char* rb = smem + (t & 1) * 65536;
        char* sb = smem + ((t & 1) ^ 1) * 65536;
        const size_t kof = (size_t)((t + 1 < nt) ? t + 1 : nt - 1) * 128;
        PHASE(0,   0,   0, rb, ST_UA0(sb, kof));
        PHASE(1, 128,   0, rb, ST_UB0(sb, kof));
        PHASE(2, 128, 128, rb, ST_UA1(sb, kof));
        PHASE(3,   0, 128, rb, ST_UB1(sb, kof));
    }
#undef PHASE
#undef ST_UA0
#undef ST_UB0
#undef ST_UA1
#undef ST_UB1

    // ---- epilogue: LDS-restage -> full-line coalesced bf16 stores ----
    {
        char* cst = smem;
        // drain dead-tail prefetches before overwriting LDS
        __builtin_amdgcn_sched_barrier(0);
        asm volatile("s_waitcnt vmcnt(0)" ::: "memory");
        pin_barrier();
        const int g4 = lg << 2;
        const int RMv[4] = {0, 128, 128, 0}, RNv[4] = {0, 0, 128, 128};
#pragma unroll
        for (int p = 0; p < 4; ++p) {
#pragma unroll
            for (int n = 0; n < 4; ++n) {
                int col = RNv[p] + wc * 64 + n * 16 + la;
                float bs = bias[col0 + col];
#pragma unroll
                for (int m = 0; m < 2; ++m) {
#pragma unroll
                    for (int r = 0; r < 4; ++r) {
                        int row = RMv[p] + wr * 32 + m * 16 + g4 + r;
                        int scol = col ^ (((row >> 2) & 3) << 3);
                        *(u16*)(cst + row * 512 + scol * 2) = f2bf(acc[p][m][n][r] + bs);
                    }
                }
            }
        }
        pin_barrier();
#pragma unroll
        for (int it = 0; it < 16; ++it) {
            int id = it * 512 + tid;       // 16B chunk: row*32 + c16
            int r2 = id >> 5, c16 = id & 31;
            int sc16 = c16 ^ ((r2 >> 2) & 3);
            u16x8 v = *(const u16x8*)(cst + r2 * 512 + sc16 * 16);
            *(u16x8*)((char*)C + ((size_t)(row0 + r2) * ldc + col0) * 2 + c16 * 16) = v;
        }
    }
}

// ====== 256x128 BK=32 GEMM (R8 structure, proven) for the output proj =======
template <int BN, bool BF16OUT>
__global__ __launch_bounds__(512, 2) void k_gemm5(
    const u16* __restrict__ A, const u16* __restrict__ B, void* __restrict__ C,
    const float* __restrict__ bias0, const float* __restrict__ bias1,
    const float* __restrict__ bias2, int K, int lda, int ldb, int ldc,
    int gxmask, int gxshift) {
    constexpr int WN = BN / 64;
    constexpr int WM = 8 / WN;
    constexpr int MFRAG = 256 / (WM * 16);
    constexpr int NBB = BN / 128;
    constexpr int NL = 2 + NBB;
    constexpr int BUFSZ = 16384 + BN * 64;

    __shared__ __align__(16) char smem[131072];
    const int tid = threadIdx.x, lane = tid & 63, wave = tid >> 6;
    const int wr = wave / WN, wc = wave % WN;

    const int nwg = gridDim.x, bid = blockIdx.x;
    const int cpx = nwg >> 3;
    const int swz = (bid & 7) * cpx + (bid >> 3);
    const int bx = swz & gxmask, by = swz >> gxshift;
    const int row0 = bx << 8, col0 = by * BN;

    const size_t lda2 = (size_t)lda * 2, ldb2 = (size_t)ldb * 2;
    const int cSw = ((tid & 3) ^ ((tid >> 3) & 3)) * 16;
    const char* pA0 = (const char*)A + (size_t)(row0 + (tid >> 2)) * lda2 + cSw;
    const char* pB0 = (const char*)B + (size_t)(col0 + (tid >> 2)) * ldb2 + cSw;

#define STA(i, sb, kof) gload16(pA0 + (size_t)(i) * 128 * lda2 + (kof), \
                                (sb) + (i) * 8192 + wave * 1024)
#define STB(i, sb, kof) gload16(pB0 + (size_t)(i) * 128 * ldb2 + (kof), \
                                (sb) + 16384 + (i) * 8192 + wave * 1024)
#define STAGE_ALL(sb, kof) do { \
        STA(0, sb, kof); STA(1, sb, kof); \
        STB(0, sb, kof); if constexpr (NBB == 2) STB(1, sb, kof); } while (0)

    auto WAIT_VM = [] {
        if constexpr (NL == 4) asm volatile("s_waitcnt vmcnt(8)" ::: "memory");
        else                   asm volatile("s_waitcnt vmcnt(6)" ::: "memory");
    };

    const int lane_off = (lane & 15) * 64 +
                         (((lane >> 4) ^ (((lane & 15) >> 1) & 3)) << 4);

    f32x4 acc[MFRAG][4] = {};
    const int nt = K >> 5;

#define TILE_BODY(q, q3, t) do { \
        char* rq = smem + (q) * BUFSZ; \
        char* sq = smem + (q3) * BUFSZ; \
        const char* aRd = rq + wr * (MFRAG * 1024) + lane_off; \
        const char* bRd = rq + 16384 + wc * 4096 + lane_off; \
        bf16x8 af[4], bg[4]; \
        _Pragma("unroll") for (int n = 0; n < 4; ++n) \
            bg[n] = *(const bf16x8*)(bRd + n * 1024); \
        _Pragma("unroll") for (int m = 0; m < 4; ++m) \
            af[m] = *(const bf16x8*)(aRd + m * 1024); \
        { \
            const int ts = ((t) + 3 < nt) ? (t) + 3 : nt - 1; \
            const size_t kof = (size_t)ts * 64; \
            STAGE_ALL(sq, kof); \
        } \
        bf16x8 ag[4]; \
        if constexpr (MFRAG == 8) { \
            _Pragma("unroll") for (int m = 0; m < 4; ++m) \
                ag[m] = *(const bf16x8*)(aRd + (4 + m) * 1024); \
        } \
        __builtin_amdgcn_sched_barrier(0); \
        __builtin_amdgcn_s_setprio(1); \
        _Pragma("unroll") for (int m = 0; m < 4; ++m) \
            _Pragma("unroll") for (int n = 0; n < 4; ++n) \
                acc[m][n] = MFMA16(af[m], bg[n], acc[m][n]); \
        __builtin_amdgcn_s_setprio(0); \
        if constexpr (MFRAG == 8) { \
            __builtin_amdgcn_sched_barrier(0); \
            __builtin_amdgcn_s_setprio(1); \
            _Pragma("unroll") for (int m = 0; m < 4; ++m) \
                _Pragma("unroll") for (int n = 0; n < 4; ++n) \
                    acc[4 + m][n] = MFMA16(ag[m], bg[n], acc[4 + m][n]); \
            __builtin_amdgcn_s_setprio(0); \
        } \
        __builtin_amdgcn_sched_barrier(0); \
        WAIT_VM(); \
        pin_barrier(); \
    } while (0)

    STAGE_ALL(smem + 0 * BUFSZ, 0);
    STAGE_ALL(smem + 1 * BUFSZ, 64);
    STAGE_ALL(smem + 2 * BUFSZ, 128);
    __builtin_amdgcn_sched_barrier(0);
    WAIT_VM();
    pin_barrier();

    for (int t = 0; t < nt; t += 4) {
        TILE_BODY(0, 3, t + 0);
        TILE_BODY(1, 0, t + 1);
        TILE_BODY(2, 1, t + 2);
        TILE_BODY(3, 2, t + 3);
    }
#undef TILE_BODY
#undef STAGE_ALL
#undef STA
#undef STB

    {
        char* cst = smem;
        const int g4 = (lane >> 4) << 2, cl = lane & 15;
        __builtin_amdgcn_sched_barrier(0);
        asm volatile("s_waitcnt vmcnt(0)" ::: "memory");
        pin_barrier();
#pragma unroll
        for (int n = 0; n < 4; ++n) {
            int col = wc * 64 + n * 16 + cl;
            float bs = bias0[col0 + col];
            if (bias1) bs += bias1[col0 + col];
            if (bias2) bs += bias2[col0 + col];
#pragma unroll
            for (int m = 0; m < MFRAG; ++m) {
#pragma unroll
                for (int r = 0; r < 4; ++r) {
                    int row = wr * (MFRAG * 16) + m * 16 + g4 + r;
                    float v = acc[m][n][r] + bs;
                    if (BF16OUT) {
                        int scol = col ^ (((row >> 2) & 3) << 3);
                        *(u16*)(cst + row * 512 + scol * 2) = f2bf(v);
                    } else {
                        int scol = col ^ (((row >> 2) & 3) << 2);
                        *(float*)(cst + row * 512 + scol * 4) = v;
                    }
                }
            }
        }
        pin_barrier();
        const int esz = BF16OUT ? 2 : 4;
#pragma unroll
        for (int it = 0; it < 16; ++it) {
            int id = it * 512 + tid;
            int row = id >> 5, c16 = id & 31;
            int sc16 = c16 ^ ((row >> 2) & 3);
            u16x8 v = *(const u16x8*)(cst + row * 512 + sc16 * 16);
            char* dst = (char*)C + ((size_t)(row0 + row) * ldc + col0) * esz + c16 * 16;
            *(u16x8*)dst = v;
        }
    }
}

// ---------------- attention: one block per (b, segment, head) ---------------
template <int S>
__global__ __launch_bounds__(256) void k_attn(const u16* __restrict__ qkv,
                                              u16* __restrict__ ab, int layer) {
    constexpr int NCT = S / 16;
    constexpr int RPW = (S == 32) ? 1 : S / 64;
    constexpr int ACTIVE = (S == 32) ? 2 : 4;
    constexpr int KST = S / 32;
    constexpr int VSTRIDE = 2 * S;
    constexpr int VMASK = VSTRIDE / 16 - 1;

    __shared__ __align__(16) char KS[S * 128];
    __shared__ __align__(16) char VTS[64 * VSTRIDE];
    __shared__ __align__(16) char PS[S * VSTRIDE];

    const int per_b = (4096 / S) * 16;
    const int b = blockIdx.x / per_b;
    const int r0 = blockIdx.x % per_b;
    const int n = r0 >> 4, h = r0 & 15;
    const int token0 = b * 4096 + n * S;
    const int colQ = layer * 3072 + h * 64;
    const int tid = threadIdx.x, lane = tid & 63, wave = tid >> 6;

    constexpr int CHUNKS = S / 32;
#pragma unroll
    for (int c = 0; c < CHUNKS; ++c) {
        int lc = c * 256 + tid;
        int row = lc >> 3, off = (lc & 7) * 16;
        const char* base = (const char*)qkv + ((size_t)(token0 + row) * 9216 + colQ) * 2 + off;
        u16x8 kv = *(const u16x8*)(base + 1024 * 2);
        *(u16x8*)(KS + row * 128 + (off ^ ((row & 7) << 4))) = kv;
        u16x8 vv = *(const u16x8*)(base + 2048 * 2);
        int cb = off >> 1;
#pragma unroll
        for (int e = 0; e < 8; ++e) {
            int col = cb + e;
            *(u16*)(VTS + col * VSTRIDE + ((row * 2) ^ ((col & VMASK) << 4))) = vv[e];
        }
    }
    __syncthreads();

    f32x4 sacc[RPW][NCT] = {};
    if (wave < ACTIVE) {
#pragma unroll
        for (int rl = 0; rl < RPW; ++rl) {
            int rt = wave * RPW + rl;
#pragma unroll
            for (int ks2 = 0; ks2 < 2; ++ks2) {
                int qrow = token0 + rt * 16 + (lane & 15);
                int kbyte = ks2 * 64 + ((lane >> 4) << 4);
                bf16x8 aq = *(const bf16x8*)((const char*)qkv +
                              ((size_t)qrow * 9216 + colQ) * 2 + kbyte);
#pragma unroll
                for (int ct = 0; ct < NCT; ++ct) {
                    int krow = ct * 16 + (lane & 15);
                    bf16x8 bk = *(const bf16x8*)(KS + krow * 128 + (kbyte ^ ((krow & 7) << 4)));
                    sacc[rl][ct] = MFMA16(aq, bk, sacc[rl][ct]);
                }
            }
        }
#pragma unroll
        for (int rl = 0; rl < RPW; ++rl) {
            int rt = wave * RPW + rl;
#pragma unroll
            for (int r = 0; r < 4; ++r) {
                float vals[NCT];
                float m = -1e30f;
#pragma unroll
                for (int ct = 0; ct < NCT; ++ct) {
                    vals[ct] = sacc[rl][ct][r] * 0.125f;
                    m = fmaxf(m, vals[ct]);
                }
#pragma unroll
                for (int d = 1; d < 16; d <<= 1) m = fmaxf(m, __shfl_xor(m, d, 64));
                float sum = 0.f;
#pragma unroll
                for (int ct = 0; ct < NCT; ++ct) {
                    float p = exp2f((vals[ct] - m) * 1.44269504f);
                    vals[ct] = p;
                    sum += p;
                }
#pragma unroll
                for (int d = 1; d < 16; d <<= 1) sum += __shfl_xor(sum, d, 64);
                float inv = 1.0f / sum;
                int row = rt * 16 + ((lane >> 4) << 2) + r;
#pragma unroll
                for (int ct = 0; ct < NCT; ++ct) {
                    int col = ct * 16 + (lane & 15);
                    *(u16*)(PS + row * VSTRIDE + ((col * 2) ^ ((row & VMASK) << 4))) =
                        f2bf(vals[ct] * inv);
                }
            }
        }
    }
    __syncthreads();

    if (wave < ACTIVE) {
        const int colA = layer * 1024 + h * 64;
#pragma unroll
        for (int rl = 0; rl < RPW; ++rl) {
            int rt = wave * RPW + rl;
            f32x4 oacc[4] = {};
#pragma unroll
            for (int ks2 = 0; ks2 < KST; ++ks2) {
                int kbyte = ks2 * 64 + ((lane >> 4) << 4);
                int prow = rt * 16 + (lane & 15);
                bf16x8 ap = *(const bf16x8*)(PS + prow * VSTRIDE + (kbyte ^ ((prow & VMASK) << 4)));
#pragma unroll
                for (int ct = 0; ct < 4; ++ct) {
                    int vcol = ct * 16 + (lane & 15);
                    bf16x8 bv = *(const bf16x8*)(VTS + vcol * VSTRIDE + (kbyte ^ ((vcol & VMASK) << 4)));
                    oacc[ct] = MFMA16(ap, bv, oacc[ct]);
                }
            }
#pragma unroll
            for (int ct = 0; ct < 4; ++ct) {
#pragma unroll
                for (int r = 0; r < 4; ++r) {
                    int row = token0 + rt * 16 + ((lane >> 4) << 2) + r;
                    int col = colA + ct * 16 + (lane & 15);
                    ab[(size_t)row * 3072 + col] = f2bf(oacc[ct][r]);
                }
            }
        }
    }
}

// ---------------------------------------------------------------------------
extern "C" void kernel_launch(void* const* d_in, const int* in_sizes, int n_in,
                              void* d_out, int out_size, void* d_ws, size_t ws_size,
                              hipStream_t stream) {
    const float* x    = (const float*)d_in[0];
    const float* Wqkv = (const float*)d_in[1];
    const float* bqkv = (const float*)d_in[2];
    const float* Wo   = (const float*)d_in[3];
    const float* bo   = (const float*)d_in[4];

    char* ws = (char*)d_ws;
    u16* XE    = (u16*)(ws);                       // [8192][1024]
    u16* WQKVT = (u16*)(ws + 16777216);            // [9216][1024]
    u16* WOT   = (u16*)(ws + 35651584);            // [1024][3072]
    u16* QKVB  = (u16*)(ws + 41943040);            // [8192][9216]
    u16* ABUF  = (u16*)(ws + 192937984);           // [8192][3072]

    k_prep_xe<<<8192, 256, 0, stream>>>(x, XE);
    k_transpose_cast<<<dim3(16, 48, 3), 256, 0, stream>>>(
        Wqkv, WQKVT, 3072, (size_t)1024 * 3072, 1024, 3072, 0);
    k_transpose_cast<<<dim3(16, 16, 3), 256, 0, stream>>>(
        Wo, WOT, 1024, (size_t)1024 * 1024, 3072, 0, 1024);

    // QKV projection for all 3 layers: [8192,1024] @ [1024,9216]
    // grid = 32 x 36 = 1152 blocks (bx fastest: mask 31, shift 5)
    k_gemm8<<<dim3(1152), 512, 0, stream>>>(
        XE, WQKVT, QKVB, bqkv, 1024, 1024, 1024, 9216, 31, 5);

    // dilated segment attention per layer
    k_attn<32><<<4096, 256, 0, stream>>>(QKVB, ABUF, 0);
    k_attn<64><<<2048, 256, 0, stream>>>(QKVB, ABUF, 1);
    k_attn<128><<<1024, 256, 0, stream>>>(QKVB, ABUF, 2);

    // fused output projection + layer sum: [8192,3072] @ [3072,1024]
    // grid = 32 x 8 = 256 blocks
    k_gemm5<128, false><<<dim3(256), 512, 0, stream>>>(
        ABUF, WOT, d_out, bo, bo + 1024, bo + 2048, 3072, 3072, 3072, 1024, 31, 5);
}

// Round 11
// 317.289 us; speedup vs baseline: 1.0504x; 1.0346x over previous
//
#include <hip/hip_runtime.h>
#include <hip/hip_bf16.h>
#include <stdint.h>

typedef unsigned short u16;
typedef short bf16x8 __attribute__((ext_vector_type(8)));
typedef u16   u16x8  __attribute__((ext_vector_type(8)));
typedef u16   u16x4  __attribute__((ext_vector_type(4)));
typedef float f32x4  __attribute__((ext_vector_type(4)));

__device__ inline u16 f2bf(float f) {
    uint32_t u = __builtin_bit_cast(uint32_t, f);
    uint32_t r = (u + 0x7FFFu + ((u >> 16) & 1u)) >> 16;
    return (u16)r;
}

__device__ inline void gload16(const void* g, void* l) {
    __builtin_amdgcn_global_load_lds((const __attribute__((address_space(1))) void*)g,
                                     (__attribute__((address_space(3))) void*)l, 16, 0, 0);
}

__device__ inline void pin_barrier() {
    __builtin_amdgcn_sched_barrier(0);
    __builtin_amdgcn_s_barrier();
    __builtin_amdgcn_sched_barrier(0);
}

#define MFMA16(a, b, c) __builtin_amdgcn_mfma_f32_16x16x32_bf16((a), (b), (c), 0, 0, 0)

// ---------------- prep: gather even rows of x, cast to bf16 -----------------
__global__ __launch_bounds__(256) void k_prep_xe(const float* __restrict__ x,
                                                 u16* __restrict__ xe) {
    int row = blockIdx.x;              // 0..8191
    int b = row >> 12, tt = row & 4095;
    const float* src = x + ((size_t)b * 8192 + 2 * (size_t)tt) * 1024;
    float4 v = ((const float4*)src)[threadIdx.x];
    u16x4 o = { f2bf(v.x), f2bf(v.y), f2bf(v.z), f2bf(v.w) };
    *(u16x4*)(xe + (size_t)row * 1024 + threadIdx.x * 4) = o;
}

// ---------------- prep: transpose + cast weights to B^T layout --------------
__global__ __launch_bounds__(256) void k_transpose_cast(
    const float* __restrict__ src, u16* __restrict__ dst,
    int srcCols, size_t srcLayerStride, int dstStride, int dstRowPer, int dstColPer) {
    int k0 = blockIdx.x * 64, e0 = blockIdx.y * 64, layer = blockIdx.z;
    const float* s = src + (size_t)layer * srcLayerStride;
    __shared__ u16 T[64][66];
    int t = threadIdx.x;
#pragma unroll
    for (int p = 0; p < 16; ++p) {
        int l = p * 256 + t;
        int kl = l >> 6, el = l & 63;
        T[kl][el] = f2bf(s[(size_t)(k0 + kl) * srcCols + e0 + el]);
    }
    __syncthreads();
    int rowBase = layer * dstRowPer + e0;
    int colBase = layer * dstColPer + k0;
#pragma unroll
    for (int p = 0; p < 16; ++p) {
        int l = p * 256 + t;
        int eo = l >> 6, ko = l & 63;
        dst[(size_t)(rowBase + eo) * dstStride + colBase + ko] = T[ko][eo];
    }
}

// ====== 256x256 BK=64 GEMM (R6 structure — best measured for GEMM1) =========
// 2 LDS buffers; 1 barrier + vmcnt(0) per tile; reg-pipelined phases (reads
// issued before the previous MFMA cluster); stage issues early in the tile.
// Swizzle: LDS row = 128B, 16B-slot ^= (row&7 low bits per R6 scheme below).
template <int BN, bool BF16OUT>
__global__ __launch_bounds__(512, 2) void k_gemm4(
    const u16* __restrict__ A, const u16* __restrict__ B, void* __restrict__ C,
    const float* __restrict__ bias0, const float* __restrict__ bias1,
    const float* __restrict__ bias2, int K, int lda, int ldb, int ldc,
    int gxmask, int gxshift) {
    constexpr int WN = BN / 64;            // waves along N (4)
    constexpr int WM = 8 / WN;             // waves along M (2)
    constexpr int MFRAG = 256 / (WM * 16); // m-frags per wave (8)
    constexpr int NB = BN / 64;            // B stage-issues per tile (4)
    constexpr int BUFSZ = 32768 + BN * 128;

    __shared__ __align__(16) char smem[131072];
    const int tid = threadIdx.x, lane = tid & 63, wave = tid >> 6;
    const int wr = wave / WN, wc = wave % WN;

    // bijective XCD swizzle (grid multiple of 8)
    const int nwg = gridDim.x, bid = blockIdx.x;
    const int cpx = nwg >> 3;
    const int swz = (bid & 7) * cpx + (bid >> 3);
    const int bx = swz & gxmask, by = swz >> gxshift;
    const int row0 = bx << 8, col0 = by * BN;

    const size_t lda2 = (size_t)lda * 2, ldb2 = (size_t)ldb * 2;
    // staging: wave-issue i covers rows i*64 + wave*8 .. +8; lane l -> local
    // row l>>3, LDS slot l&7 holding global 16B-chunk (l&7)^(l>>3).
    const char* pA0 = (const char*)A +
        (size_t)(row0 + wave * 8 + (lane >> 3)) * lda2 + ((lane & 7) ^ (lane >> 3)) * 16;
    const char* pB0 = (const char*)B +
        (size_t)(col0 + wave * 8 + (lane >> 3)) * ldb2 + ((lane & 7) ^ (lane >> 3)) * 16;

#define STA(i, sb, kof) gload16(pA0 + (size_t)(i) * 64 * lda2 + (kof), (sb) + ((i) * 8 + wave) * 1024)
#define STB(i, sb, kof) gload16(pB0 + (size_t)(i) * 64 * ldb2 + (kof), (sb) + 32768 + ((i) * 8 + wave) * 1024)

    // frag ds_read offsets: row = ...+ (lane&15); slot = (kh*4 + lane>>4) ^ (row&7)
    const int la = lane & 15, lg = lane >> 4, l7 = lane & 7;
    const int offK0 = la * 128 + ((lg ^ l7) << 4);
    const int offK1 = la * 128 + (((4 + lg) ^ l7) << 4);

    f32x4 acc[MFRAG][4] = {};
    const int nt = K >> 6;

    char* const BUF0 = smem;
    char* const BUF1 = smem + BUFSZ;

    // prologue: stage tile 0 into BUF0, drain once
    {
#pragma unroll
        for (int i = 0; i < 4; ++i) STA(i, BUF0, 0);
#pragma unroll
        for (int i = 0; i < NB; ++i) STB(i, BUF0, 0);
        __builtin_amdgcn_sched_barrier(0);
        asm volatile("s_waitcnt vmcnt(0)" ::: "memory");
        pin_barrier();
    }

    for (int t = 0; t < nt; ++t) {
        char* rq = (t & 1) ? BUF1 : BUF0;
        char* sq = (t & 1) ? BUF0 : BUF1;
        const bool st = (t + 1 < nt);
        const size_t kof = (size_t)(t + 1) * 128;
        const char* aB = rq + wr * (MFRAG * 2048);
        const char* bB = rq + 32768 + wc * 8192;

        bf16x8 af[4], ag[4], b0[4], b1[4];
#pragma unroll
        for (int n = 0; n < 4; ++n) b0[n] = *(const bf16x8*)(bB + n * 2048 + offK0);
#pragma unroll
        for (int m = 0; m < 4; ++m) af[m] = *(const bf16x8*)(aB + m * 2048 + offK0);
        if (st) { STA(0, sq, kof); STA(1, sq, kof); }
#pragma unroll
        for (int m = 0; m < 4; ++m)
            ag[m] = *(const bf16x8*)(aB + 8192 + m * 2048 + offK0);
#pragma unroll
        for (int n = 0; n < 4; ++n) b1[n] = *(const bf16x8*)(bB + n * 2048 + offK1);
        if (st) {
            STA(2, sq, kof); STA(3, sq, kof);
#pragma unroll
            for (int i = 0; i < NB; ++i) STB(i, sq, kof);
        }
        // phase 0: acc[0..3] += af(kh0) x b0
        __builtin_amdgcn_s_setprio(1);
#pragma unroll
        for (int m = 0; m < 4; ++m)
#pragma unroll
            for (int n = 0; n < 4; ++n)
                acc[m][n] = MFMA16(af[m], b0[n], acc[m][n]);
        __builtin_amdgcn_s_setprio(0);
        __builtin_amdgcn_sched_barrier(0);
        // phase 1 reads (m0-3 kh1), MFMA acc[4..7] += ag(kh0) x b0
#pragma unroll
        for (int m = 0; m < 4; ++m) af[m] = *(const bf16x8*)(aB + m * 2048 + offK1);
        __builtin_amdgcn_s_setprio(1);
#pragma unroll
        for (int m = 0; m < 4; ++m)
#pragma unroll
            for (int n = 0; n < 4; ++n)
                acc[4 + m][n] = MFMA16(ag[m], b0[n], acc[4 + m][n]);
        __builtin_amdgcn_s_setprio(0);
        __builtin_amdgcn_sched_barrier(0);
        // phase 2 reads (m4-7 kh1), MFMA acc[0..3] += af(kh1) x b1
#pragma unroll
        for (int m = 0; m < 4; ++m)
            ag[m] = *(const bf16x8*)(aB + 8192 + m * 2048 + offK1);
        __builtin_amdgcn_s_setprio(1);
#pragma unroll
        for (int m = 0; m < 4; ++m)
#pragma unroll
            for (int n = 0; n < 4; ++n)
                acc[m][n] = MFMA16(af[m], b1[n], acc[m][n]);
        __builtin_amdgcn_s_setprio(0);
        __builtin_amdgcn_sched_barrier(0);
        // phase 3 MFMA: acc[4..7] += ag(kh1) x b1
        __builtin_amdgcn_s_setprio(1);
#pragma unroll
        for (int m = 0; m < 4; ++m)
#pragma unroll
            for (int n = 0; n < 4; ++n)
                acc[4 + m][n] = MFMA16(ag[m], b1[n], acc[4 + m][n]);
        __builtin_amdgcn_s_setprio(0);
        // single end-of-tile sync
        __builtin_amdgcn_sched_barrier(0);
        asm volatile("s_waitcnt vmcnt(0)" ::: "memory");
        pin_barrier();
    }
#undef STA
#undef STB

    // ---- epilogue: LDS-restage -> full-line coalesced stores ----
    {
        char* cst = smem;
        const int g4 = (lane >> 4) << 2, cl = lane & 15;
#pragma unroll
        for (int n = 0; n < 4; ++n) {
            int col = wc * 64 + n * 16 + cl;
            float bs = bias0[col0 + col];
            if (bias1) bs += bias1[col0 + col];
            if (bias2) bs += bias2[col0 + col];
#pragma unroll
            for (int m = 0; m < MFRAG; ++m) {
#pragma unroll
                for (int r = 0; r < 4; ++r) {
                    int row = wr * (MFRAG * 16) + m * 16 + g4 + r;
                    float v = acc[m][n][r] + bs;
                    if (BF16OUT) {
                        int scol = col ^ (((row >> 2) & 3) << 3);
                        *(u16*)(cst + row * 512 + scol * 2) = f2bf(v);
                    } else {
                        int scol = col ^ (((row >> 2) & 3) << 2);
                        *(float*)(cst + row * 512 + scol * 4) = v;
                    }
                }
            }
        }
        pin_barrier();
        const int esz = BF16OUT ? 2 : 4;
#pragma unroll
        for (int it = 0; it < 16; ++it) {
            int id = it * 512 + tid;       // 16B chunk: row*32 + c16
            int row = id >> 5, c16 = id & 31;
            int sc16 = c16 ^ ((row >> 2) & 3);
            u16x8 v = *(const u16x8*)(cst + row * 512 + sc16 * 16);
            char* dst = (char*)C + ((size_t)(row0 + row) * ldc + col0) * esz + c16 * 16;
            *(u16x8*)dst = v;
        }
    }
}

// ====== NEW: 128x128 BK=64 GEMM, 4 waves, 2 blocks/CU (output projection) ===
// Per-wave 64x64 (acc 64 AGPR); 2x32KB LDS buffers; drain+barrier per tile;
// the SECOND resident block on each CU covers the stalls (m97-TLP mechanism).
// Swizzle: 128B rows, 16B-slot ^= (row&7) (R10-proven free), inverse-swizzled
// global source (linear gload_lds dest), swizzled ds_read.
// f32 output, 3 biases summed. Requires K%64==0, M%128==0, N%128==0, grid%8==0.
__global__ __launch_bounds__(256, 2) void k_gemm4b(
    const u16* __restrict__ A, const u16* __restrict__ B, float* __restrict__ C,
    const float* __restrict__ bias0, const float* __restrict__ bias1,
    const float* __restrict__ bias2, int K, int lda, int ldb, int ldc,
    int gxmask, int gxshift) {
    __shared__ __align__(16) char smem[65536];
    const int tid = threadIdx.x, lane = tid & 63, wave = tid >> 6;
    const int wr = wave >> 1, wc = wave & 1;   // 2M x 2N

    // bijective XCD swizzle (grid multiple of 8)
    const int nwg = gridDim.x, bid = blockIdx.x;
    const int cpx = nwg >> 3;
    const int swz = (bid & 7) * cpx + (bid >> 3);
    const int bx = swz & gxmask, by = swz >> gxshift;
    const int row0 = bx << 7, col0 = by << 7;

    const size_t lda2 = (size_t)lda * 2, ldb2 = (size_t)ldb * 2;
    // staging: chunk c = tid + i*256 -> row = (tid>>3) + i*32, slot = tid&7;
    // source 16B-chunk = (tid&7) ^ ((tid>>3)&7). Dest byte = i*4096 + tid*16.
    const int sRow = tid >> 3;
    const int sChunk = (tid & 7) ^ (sRow & 7);
    const char* pA0 = (const char*)A + (size_t)(row0 + sRow) * lda2 + sChunk * 16;
    const char* pB0 = (const char*)B + (size_t)(col0 + sRow) * ldb2 + sChunk * 16;

#define STA_(i, sb, kof) gload16(pA0 + (size_t)(i) * 32 * lda2 + (kof), \
                                 (sb) + (i) * 4096 + wave * 1024)
#define STB_(i, sb, kof) gload16(pB0 + (size_t)(i) * 32 * ldb2 + (kof), \
                                 (sb) + 16384 + (i) * 4096 + wave * 1024)

    // frag ds_read offsets: row = base + la, slot = (kh*4 + lg) ^ (la&7)
    const int la = lane & 15, lg = lane >> 4;
    const int loff0 = la * 128 + (((lg) ^ (la & 7)) << 4);
    const int loff1 = la * 128 + (((4 + lg) ^ (la & 7)) << 4);

    f32x4 acc[4][4] = {};
    const int nt = K >> 6;

    // prologue: stage tile 0 into buf0, drain once
#pragma unroll
    for (int i = 0; i < 4; ++i) STA_(i, smem, 0);
#pragma unroll
    for (int i = 0; i < 4; ++i) STB_(i, smem, 0);
    __builtin_amdgcn_sched_barrier(0);
    asm volatile("s_waitcnt vmcnt(0)" ::: "memory");
    pin_barrier();

    for (int t = 0; t < nt; ++t) {
        char* rq = smem + (t & 1) * 32768;
        char* sq = smem + ((t & 1) ^ 1) * 32768;
        const bool st = (t + 1 < nt);
        const size_t kof = (size_t)(t + 1) * 128;
        const char* aB = rq + wr * 8192;
        const char* bB = rq + 16384 + wc * 8192;

        bf16x8 a0[4], a1[4], b0f[4], b1f[4];
#pragma unroll
        for (int n = 0; n < 4; ++n) b0f[n] = *(const bf16x8*)(bB + n * 2048 + loff0);
#pragma unroll
        for (int m = 0; m < 4; ++m) a0[m] = *(const bf16x8*)(aB + m * 2048 + loff0);
        if (st) { STA_(0, sq, kof); STA_(1, sq, kof); STA_(2, sq, kof); STA_(3, sq, kof); }
#pragma unroll
        for (int n = 0; n < 4; ++n) b1f[n] = *(const bf16x8*)(bB + n * 2048 + loff1);
#pragma unroll
        for (int m = 0; m < 4; ++m) a1[m] = *(const bf16x8*)(aB + m * 2048 + loff1);
        if (st) { STB_(0, sq, kof); STB_(1, sq, kof); STB_(2, sq, kof); STB_(3, sq, kof); }

        __builtin_amdgcn_sched_barrier(0);
        __builtin_amdgcn_s_setprio(1);
#pragma unroll
        for (int m = 0; m < 4; ++m)
#pragma unroll
            for (int n = 0; n < 4; ++n)
                acc[m][n] = MFMA16(a0[m], b0f[n], acc[m][n]);
        __builtin_amdgcn_s_setprio(0);
        __builtin_amdgcn_sched_barrier(0);
        __builtin_amdgcn_s_setprio(1);
#pragma unroll
        for (int m = 0; m < 4; ++m)
#pragma unroll
            for (int n = 0; n < 4; ++n)
                acc[m][n] = MFMA16(a1[m], b1f[n], acc[m][n]);
        __builtin_amdgcn_s_setprio(0);
        __builtin_amdgcn_sched_barrier(0);
        asm volatile("s_waitcnt vmcnt(0)" ::: "memory");
        pin_barrier();
    }
#undef STA_
#undef STB_

    // ---- epilogue: single-pass 64KB LDS restage -> coalesced f32 stores ----
    {
        float* cst = (float*)smem;
        const int g4 = lg << 2;
#pragma unroll
        for (int n = 0; n < 4; ++n) {
            int col = wc * 64 + n * 16 + la;
            float bs = bias0[col0 + col] + bias1[col0 + col] + bias2[col0 + col];
#pragma unroll
            for (int m = 0; m < 4; ++m) {
#pragma unroll
                for (int r = 0; r < 4; ++r) {
                    int row = wr * 64 + m * 16 + g4 + r;
                    int scol = col ^ (((row >> 2) & 3) << 3);
                    cst[row * 128 + scol] = acc[m][n][r] + bs;
                }
            }
        }
        pin_barrier();
#pragma unroll
        for (int it = 0; it < 16; ++it) {
            int id = it * 256 + tid;       // 16B chunk: row*32 + c16
            int row = id >> 5, c16 = id & 31;
            int sc16 = c16 ^ (((row >> 2) & 3) << 1);
            u16x8 v = *(const u16x8*)((char*)cst + row * 512 + sc16 * 16);
            *(u16x8*)((char*)C + ((size_t)(row0 + row) * ldc + col0) * 4 + c16 * 16) = v;
        }
    }
}

// ---------------- attention: one block per (b, segment, head) ---------------
template <int S>
__global__ __launch_bounds__(256) void k_attn(const u16* __restrict__ qkv,
                                              u16* __restrict__ ab, int layer) {
    constexpr int NCT = S / 16;
    constexpr int RPW = (S == 32) ? 1 : S / 64;
    constexpr int ACTIVE = (S == 32) ? 2 : 4;
    constexpr int KST = S / 32;
    constexpr int VSTRIDE = 2 * S;
    constexpr int VMASK = VSTRIDE / 16 - 1;

    __shared__ __align__(16) char KS[S * 128];
    __shared__ __align__(16) char VTS[64 * VSTRIDE];
    __shared__ __align__(16) char PS[S * VSTRIDE];

    const int per_b = (4096 / S) * 16;
    const int b = blockIdx.x / per_b;
    const int r0 = blockIdx.x % per_b;
    const int n = r0 >> 4, h = r0 & 15;
    const int token0 = b * 4096 + n * S;
    const int colQ = layer * 3072 + h * 64;
    const int tid = threadIdx.x, lane = tid & 63, wave = tid >> 6;

    constexpr int CHUNKS = S / 32;
#pragma unroll
    for (int c = 0; c < CHUNKS; ++c) {
        int lc = c * 256 + tid;
        int row = lc >> 3, off = (lc & 7) * 16;
        const char* base = (const char*)qkv + ((size_t)(token0 + row) * 9216 + colQ) * 2 + off;
        u16x8 kv = *(const u16x8*)(base + 1024 * 2);
        *(u16x8*)(KS + row * 128 + (off ^ ((row & 7) << 4))) = kv;
        u16x8 vv = *(const u16x8*)(base + 2048 * 2);
        int cb = off >> 1;
#pragma unroll
        for (int e = 0; e < 8; ++e) {
            int col = cb + e;
            *(u16*)(VTS + col * VSTRIDE + ((row * 2) ^ ((col & VMASK) << 4))) = vv[e];
        }
    }
    __syncthreads();

    f32x4 sacc[RPW][NCT] = {};
    if (wave < ACTIVE) {
#pragma unroll
        for (int rl = 0; rl < RPW; ++rl) {
            int rt = wave * RPW + rl;
#pragma unroll
            for (int ks2 = 0; ks2 < 2; ++ks2) {
                int qrow = token0 + rt * 16 + (lane & 15);
                int kbyte = ks2 * 64 + ((lane >> 4) << 4);
                bf16x8 aq = *(const bf16x8*)((const char*)qkv +
                              ((size_t)qrow * 9216 + colQ) * 2 + kbyte);
#pragma unroll
                for (int ct = 0; ct < NCT; ++ct) {
                    int krow = ct * 16 + (lane & 15);
                    bf16x8 bk = *(const bf16x8*)(KS + krow * 128 + (kbyte ^ ((krow & 7) << 4)));
                    sacc[rl][ct] = MFMA16(aq, bk, sacc[rl][ct]);
                }
            }
        }
#pragma unroll
        for (int rl = 0; rl < RPW; ++rl) {
            int rt = wave * RPW + rl;
#pragma unroll
            for (int r = 0; r < 4; ++r) {
                float vals[NCT];
                float m = -1e30f;
#pragma unroll
                for (int ct = 0; ct < NCT; ++ct) {
                    vals[ct] = sacc[rl][ct][r] * 0.125f;
                    m = fmaxf(m, vals[ct]);
                }
#pragma unroll
                for (int d = 1; d < 16; d <<= 1) m = fmaxf(m, __shfl_xor(m, d, 64));
                float sum = 0.f;
#pragma unroll
                for (int ct = 0; ct < NCT; ++ct) {
                    float p = exp2f((vals[ct] - m) * 1.44269504f);
                    vals[ct] = p;
                    sum += p;
                }
#pragma unroll
                for (int d = 1; d < 16; d <<= 1) sum += __shfl_xor(sum, d, 64);
                float inv = 1.0f / sum;
                int row = rt * 16 + ((lane >> 4) << 2) + r;
#pragma unroll
                for (int ct = 0; ct < NCT; ++ct) {
                    int col = ct * 16 + (lane & 15);
                    *(u16*)(PS + row * VSTRIDE + ((col * 2) ^ ((row & VMASK) << 4))) =
                        f2bf(vals[ct] * inv);
                }
            }
        }
    }
    __syncthreads();

    if (wave < ACTIVE) {
        const int colA = layer * 1024 + h * 64;
#pragma unroll
        for (int rl = 0; rl < RPW; ++rl) {
            int rt = wave * RPW + rl;
            f32x4 oacc[4] = {};
#pragma unroll
            for (int ks2 = 0; ks2 < KST; ++ks2) {
                int kbyte = ks2 * 64 + ((lane >> 4) << 4);
                int prow = rt * 16 + (lane & 15);
                bf16x8 ap = *(const bf16x8*)(PS + prow * VSTRIDE + (kbyte ^ ((prow & VMASK) << 4)));
#pragma unroll
                for (int ct = 0; ct < 4; ++ct) {
                    int vcol = ct * 16 + (lane & 15);
                    bf16x8 bv = *(const bf16x8*)(VTS + vcol * VSTRIDE + (kbyte ^ ((vcol & VMASK) << 4)));
                    oacc[ct] = MFMA16(ap, bv, oacc[ct]);
                }
            }
#pragma unroll
            for (int ct = 0; ct < 4; ++ct) {
#pragma unroll
                for (int r = 0; r < 4; ++r) {
                    int row = token0 + rt * 16 + ((lane >> 4) << 2) + r;
                    int col = colA + ct * 16 + (lane & 15);
                    ab[(size_t)row * 3072 + col] = f2bf(oacc[ct][r]);
                }
            }
        }
    }
}

// ---------------------------------------------------------------------------
extern "C" void kernel_launch(void* const* d_in, const int* in_sizes, int n_in,
                              void* d_out, int out_size, void* d_ws, size_t ws_size,
                              hipStream_t stream) {
    const float* x    = (const float*)d_in[0];
    const float* Wqkv = (const float*)d_in[1];
    const float* bqkv = (const float*)d_in[2];
    const float* Wo   = (const float*)d_in[3];
    const float* bo   = (const float*)d_in[4];

    char* ws = (char*)d_ws;
    u16* XE    = (u16*)(ws);                       // [8192][1024]
    u16* WQKVT = (u16*)(ws + 16777216);            // [9216][1024]
    u16* WOT   = (u16*)(ws + 35651584);            // [1024][3072]
    u16* QKVB  = (u16*)(ws + 41943040);            // [8192][9216]
    u16* ABUF  = (u16*)(ws + 192937984);           // [8192][3072]

    k_prep_xe<<<8192, 256, 0, stream>>>(x, XE);
    k_transpose_cast<<<dim3(16, 48, 3), 256, 0, stream>>>(
        Wqkv, WQKVT, 3072, (size_t)1024 * 3072, 1024, 3072, 0);
    k_transpose_cast<<<dim3(16, 16, 3), 256, 0, stream>>>(
        Wo, WOT, 1024, (size_t)1024 * 1024, 3072, 0, 1024);

    // QKV projection for all 3 layers: [8192,1024] @ [1024,9216]
    // grid = 32 x 36 = 1152 blocks (bx fastest: mask 31, shift 5)
    k_gemm4<256, true><<<dim3(1152), 512, 0, stream>>>(
        XE, WQKVT, QKVB, bqkv, nullptr, nullptr, 1024, 1024, 1024, 9216, 31, 5);

    // dilated segment attention per layer
    k_attn<32><<<4096, 256, 0, stream>>>(QKVB, ABUF, 0);
    k_attn<64><<<2048, 256, 0, stream>>>(QKVB, ABUF, 1);
    k_attn<128><<<1024, 256, 0, stream>>>(QKVB, ABUF, 2);

    // fused output projection + layer sum: [8192,3072] @ [3072,1024]
    // grid = 64 x 8 = 512 blocks, 128x128 tile, 2 blocks/CU
    k_gemm4b<<<dim3(512), 256, 0, stream>>>(
        ABUF, WOT, (float*)d_out, bo, bo + 1024, bo + 2048,
        3072, 3072, 3072, 1024, 63, 6);
}